// Round 1
// baseline (652.879 us; speedup 1.0000x reference)
//
#include <hip/hip_runtime.h>

// Problem constants
#define LQN   16384     // queries per batch (128*128)
#define LINN  65536     // value length per batch (4 levels * 16384)

typedef __attribute__((ext_vector_type(8))) short bf16x8;
typedef __attribute__((ext_vector_type(4))) float f32x4;
typedef __attribute__((ext_vector_type(4))) unsigned short bf16x4;

__device__ __forceinline__ unsigned short f2bf(float f) {
  unsigned u = __float_as_uint(f);
  u += 0x7FFFu + ((u >> 16) & 1u);      // round-to-nearest-even
  return (unsigned short)(u >> 16);
}

// ---------------- fused weight transpose+convert for all 6 weights.
// wt layout (shorts): W_val[0,65536) W_off[65536,131072) W_attn[131072,163840)
// W_out[163840,229376) W1[229376,491520) W2[491520,753664). Total 753664.
// NOTE: W_off then W_attn contiguous => combined 384xK matrix for the merged GEMM.
__global__ __launch_bounds__(256) void wtrans6_kernel(
    const float* __restrict__ Wv, const float* __restrict__ Wo,
    const float* __restrict__ Wa, const float* __restrict__ Wu,
    const float* __restrict__ W1, const float* __restrict__ W2,
    unsigned short* __restrict__ wt) {
  int idx = blockIdx.x * 256 + threadIdx.x;     // grid = 2944 blocks exactly
  const float* W; int K, N, base;
  if (idx < 131072) {
    if (idx < 65536) { W = Wv; K = 256; N = 256; base = 0; }
    else             { W = Wo; K = 256; N = 256; base = 65536; }
  } else if (idx < 229376) {
    if (idx < 163840) { W = Wa; K = 256; N = 128; base = 131072; }
    else              { W = Wu; K = 256; N = 256; base = 163840; }
  } else if (idx < 491520) { W = W1; K = 256; N = 1024; base = 229376; }
  else                     { W = W2; K = 1024; N = 256; base = 491520; }
  int local = idx - base;
  int n = local / K, k = local - n * K;
  wt[idx] = f2bf(W[(size_t)k * N + n]);
}

// ---------------- streaming add+convert: inp_bf = bf16(src_all + pos_flat).
// Level-3 threads additionally produce qbuf = bf16(cur_src + pos[:,3]),
// reusing the already-loaded pos register (saves re-streaming pos[:,3]).
__global__ __launch_bounds__(256) void addcvt_kernel(
    const float* __restrict__ src_all, const float* __restrict__ pos,
    const float* __restrict__ cur, unsigned short* __restrict__ inp_bf,
    unsigned short* __restrict__ qb) {
  size_t i = (size_t)blockIdx.x * 256 + threadIdx.x;  // < 8388608 (grid 32768)
  float4 a = ((const float4*)src_all)[i];
  float4 b = ((const float4*)pos)[i];     // pos flat matches src_all row order
  bf16x4 o;
  o.x = f2bf(a.x + b.x); o.y = f2bf(a.y + b.y);
  o.z = f2bf(a.z + b.z); o.w = f2bf(a.w + b.w);
  ((bf16x4*)inp_bf)[i] = o;
  size_t m = i & 4194303;                 // within-batch float4 index (2^22)
  if (m >= 3145728) {                     // level-3 slice of pos
    size_t jq = (i >> 22) * 1048576 + (m - 3145728);
    float4 cc = ((const float4*)cur)[jq];
    bf16x4 o2;
    o2.x = f2bf(cc.x + b.x); o2.y = f2bf(cc.y + b.y);
    o2.z = f2bf(cc.z + b.z); o2.w = f2bf(cc.w + b.w);
    ((bf16x4*)qb)[jq] = o2;
  }
}

// ---------------- bf16 MFMA GEMM, m97-style global_load_lds staging.
// A: M x K bf16 row-major. Bt: N x K bf16 (pre-transposed). 128x128 tile,
// BK=64, 4 waves (2x2 of 64x64). LDS unpadded, XOR source-swizzle: physical
// 16B chunk p of row r holds logical chunk p^(r&7); reads become 2-way (free).
// 1D grid, y-fast: by = bid % ny (N tile), bx = bid / ny (M tile).
// SPLIT=1: cols [0,256) -> Cp (stride 256) + bias, cols [256,384) -> Cp2
// (stride 128) + bias2 (block-uniform branch; tiles are pure).
template <int DO_RELU, int OUT_BF16, int SPLIT>
__global__ __launch_bounds__(256) void gemm_lds_kernel(
    const unsigned short* __restrict__ A, const unsigned short* __restrict__ Bt,
    const float* __restrict__ bias, const float* __restrict__ bias2,
    void* __restrict__ Cp, float* __restrict__ Cp2,
    int M, int N, int K, int ny) {
  __shared__ unsigned short As[128 * 64];
  __shared__ unsigned short Bs[128 * 64];
  const int bid = blockIdx.x;
  const int by = bid % ny, bx = bid / ny;
  const int m0 = bx * 128, n0 = by * 128;
  const int tid = threadIdx.x;
  const int wave = tid >> 6, lane = tid & 63;
  const int wm = (wave >> 1) * 64, wn = (wave & 1) * 64;
  const int l15 = lane & 15, quad = lane >> 4;
  const int rl = lane >> 3;                 // row within 8-row slab
  const int cl = (lane & 7) ^ rl;           // swizzled source chunk (16B units)

  f32x4 acc[4][4];
#pragma unroll
  for (int i = 0; i < 4; i++)
#pragma unroll
    for (int j = 0; j < 4; j++)
#pragma unroll
      for (int r = 0; r < 4; r++) acc[i][j][r] = 0.f;

  const unsigned short* Abase = A + (size_t)m0 * K + cl * 8;
  const unsigned short* Bbase = Bt + (size_t)n0 * K + cl * 8;

  for (int k0 = 0; k0 < K; k0 += 64) {
    // ---- async stage: each wave covers 32 rows of As and Bs (4 issues each)
#pragma unroll
    for (int t = 0; t < 4; t++) {
      const int row = wave * 32 + t * 8 + rl;
      __builtin_amdgcn_global_load_lds(
          (const __attribute__((address_space(1))) void*)(Abase + (size_t)row * K + k0),
          (__attribute__((address_space(3))) void*)(As + (wave * 32 + t * 8) * 64),
          16, 0, 0);
      __builtin_amdgcn_global_load_lds(
          (const __attribute__((address_space(1))) void*)(Bbase + (size_t)row * K + k0),
          (__attribute__((address_space(3))) void*)(Bs + (wave * 32 + t * 8) * 64),
          16, 0, 0);
    }
    __syncthreads();   // drains vmcnt(0) then barrier: LDS tiles ready
#pragma unroll
    for (int kk = 0; kk < 2; kk++) {
      bf16x8 af[4], bfr[4];
#pragma unroll
      for (int i = 0; i < 4; i++) {
        const int row = wm + i * 16 + l15;
        af[i] = *(const bf16x8*)&As[row * 64 + (((quad + 4 * kk) ^ (row & 7)) * 8)];
      }
#pragma unroll
      for (int j = 0; j < 4; j++) {
        const int row = wn + j * 16 + l15;
        bfr[j] = *(const bf16x8*)&Bs[row * 64 + (((quad + 4 * kk) ^ (row & 7)) * 8)];
      }
#pragma unroll
      for (int i = 0; i < 4; i++)
#pragma unroll
        for (int j = 0; j < 4; j++)
          acc[i][j] = __builtin_amdgcn_mfma_f32_16x16x32_bf16(af[i], bfr[j], acc[i][j], 0, 0, 0);
    }
    __syncthreads();   // protect LDS before next-iter overwrite
  }
  // ---- epilogue: bias (+relu), store
#pragma unroll
  for (int i = 0; i < 4; i++) {
#pragma unroll
    for (int j = 0; j < 4; j++) {
      const int col = n0 + wn + j * 16 + l15;
      float bv;
      if (SPLIT) bv = (col < 256) ? bias[col] : bias2[col - 256];
      else       bv = bias[col];
#pragma unroll
      for (int r = 0; r < 4; r++) {
        const int row = m0 + wm + i * 16 + quad * 4 + r;
        float v = acc[i][j][r] + bv;
        if (DO_RELU) v = fmaxf(v, 0.f);
        if (SPLIT) {
          if (col < 256) ((float*)Cp)[(size_t)row * 256 + col] = v;
          else           Cp2[(size_t)row * 128 + (col - 256)] = v;
        } else if (OUT_BF16) {
          ((unsigned short*)Cp)[(size_t)row * N + col] = f2bf(v);
        } else {
          ((float*)Cp)[(size_t)row * N + col] = v;
        }
      }
    }
  }
}

// ---------------- deformable sampling (v2)
// value: (2, LINN, 8, 32) bf16; offs: (2,LQ,8,4,4,2) f32; attnl: (2,LQ,128) f32;
// refp: (2,LQ,4,2) f32; out: (2,LQ,8,32) bf16 written as uint2 per lane.
// 8-lane subgroup per (n,lq,h); lane cl handles channels 4cl..4cl+3 (2 uints,
// dwordx2 gathers -> half the VMEM instructions of the 16-lane version).
// Softmax distributed (lane owns 2 logits, shfl_xor tree). Per-point corner
// weights + packed pixel ids staged in LDS by the owning lane, read back with
// ds_read_b128/b32 broadcast (replaces 5 ds_bpermute per point). All gather
// addresses are uniform_base + 32-bit byte offset (saddr form).
__global__ __launch_bounds__(256) void sample_kernel(
    const unsigned short* __restrict__ value, const float* __restrict__ offs,
    const float* __restrict__ attnl, const float* __restrict__ refp,
    unsigned int* __restrict__ attn_out) {
  __shared__ float wlds[32 * 16 * 8];      // [sub][pt][w00 w01 w10 w11 pk . . .]
  const int tid = threadIdx.x;
  const int sub = tid >> 3;                // 0..31
  const int cl  = tid & 7;                 // lane in subgroup
  const int g = blockIdx.x * 32 + sub;     // (n*LQ+lq)*8 + h, < 262144
  const int n = g >> 17;
  const int nl = g >> 3;                   // n*LQ + lq
  const int h = g & 7;

  // ---- distributed softmax over 16 (level,point) logits; lane owns 2cl,2cl+1
  const float* lg = attnl + (size_t)nl * 128 + h * 16;
  const float2 l2 = *(const float2*)(lg + 2 * cl);
  float mx = fmaxf(l2.x, l2.y);
#pragma unroll
  for (int o = 1; o < 8; o <<= 1) mx = fmaxf(mx, __shfl_xor(mx, o, 8));
  const float e0 = __expf(l2.x - mx), e1 = __expf(l2.y - mx);
  float s = e0 + e1;
#pragma unroll
  for (int o = 1; o < 8; o <<= 1) s += __shfl_xor(s, o, 8);
  const float inv = 1.f / s;

  // ---- prep 2 points per lane: pt = 2cl, 2cl+1 -> LDS
  const float4 o4 = *(const float4*)(offs + (size_t)g * 32 + 4 * cl);
  const float2 r2 = *(const float2*)(refp + ((size_t)nl * 4 + (cl >> 1)) * 2);
#pragma unroll
  for (int q = 0; q < 2; q++) {
    const float ox = (q == 0) ? o4.x : o4.z;
    const float oy = (q == 0) ? o4.y : o4.w;
    const float aw = ((q == 0) ? e0 : e1) * inv;
    const float x = fmaf(r2.x, 128.f, ox - 0.5f);   // (ref + off/128)*128 - 0.5
    const float y = fmaf(r2.y, 128.f, oy - 0.5f);
    const float xf = floorf(x), yf = floorf(y);
    const float fx = x - xf, fy = y - yf;
    const int x0 = (int)xf, y0 = (int)yf;
    const int xc0 = min(max(x0, 0), 127), xc1 = min(max(x0 + 1, 0), 127);
    const int yc0 = min(max(y0, 0), 127), yc1 = min(max(y0 + 1, 0), 127);
    const float wx0 = (x0 >= 0 && x0 <= 127) ? (1.f - fx) : 0.f;
    const float wx1 = (x0 >= -1 && x0 <= 126) ? fx : 0.f;
    const float wy0 = ((y0 >= 0 && y0 <= 127) ? (1.f - fy) : 0.f) * aw;
    const float wy1 = ((y0 >= -1 && y0 <= 126) ? fy : 0.f) * aw;
    const int p00 = yc0 * 128 + xc0;          // 14 bits
    const int p11 = yc1 * 128 + xc1;          // 14 bits
    const int dxp = xc1 - xc0;                // 0 or 1
    const unsigned pk = (unsigned)p00 | ((unsigned)p11 << 14) | ((unsigned)dxp << 28);
    const int pt = 2 * cl + q;
    float4 w4;
    w4.x = wx0 * wy0; w4.y = wx1 * wy0; w4.z = wx0 * wy1; w4.w = wx1 * wy1;
    *(float4*)&wlds[(sub * 16 + pt) * 8] = w4;
    wlds[(sub * 16 + pt) * 8 + 4] = __uint_as_float(pk);
  }

  // ---- gather loop: 16 points, 4 corners each, dwordx2 per corner
  const char* vb = (const char*)value;
  const unsigned baseidx = ((unsigned)n << 23) + (unsigned)(h * 16 + 2 * cl);  // uint units
  float a0 = 0.f, a1 = 0.f, a2 = 0.f, a3 = 0.f;
#pragma unroll
  for (int p = 0; p < 16; p++) {
    const float4 w4 = *(const float4*)&wlds[(sub * 16 + p) * 8];
    const unsigned pk = __float_as_uint(wlds[(sub * 16 + p) * 8 + 4]);
    const unsigned lb = (unsigned)(p >> 2) * 2097152u;   // level base (uints)
    const unsigned p00 = pk & 16383u;
    const unsigned p11 = (pk >> 14) & 16383u;
    const unsigned d128 = (pk >> 28) << 7;               // dx * pixel stride
    const unsigned iA = baseidx + (lb + p00 * 128u);     // (y0,x0)
    const unsigned iB = baseidx + (lb + p11 * 128u);     // (y1,x1)
    const uint2 v00 = *(const uint2*)(vb + ((iA) << 2));
    const uint2 v01 = *(const uint2*)(vb + ((iA + d128) << 2));
    const uint2 v11 = *(const uint2*)(vb + ((iB) << 2));
    const uint2 v10 = *(const uint2*)(vb + ((iB - d128) << 2));
#define ACC4(vv, w)                                             \
    a0 = fmaf(w, __uint_as_float((vv).x << 16), a0);            \
    a1 = fmaf(w, __uint_as_float((vv).x & 0xFFFF0000u), a1);    \
    a2 = fmaf(w, __uint_as_float((vv).y << 16), a2);            \
    a3 = fmaf(w, __uint_as_float((vv).y & 0xFFFF0000u), a3);
    ACC4(v00, w4.x)
    ACC4(v01, w4.y)
    ACC4(v10, w4.z)
    ACC4(v11, w4.w)
#undef ACC4
  }
  uint2 o;
  o.x = (unsigned)f2bf(a0) | ((unsigned)f2bf(a1) << 16);
  o.y = (unsigned)f2bf(a2) | ((unsigned)f2bf(a3) << 16);
  ((uint2*)attn_out)[(size_t)g * 8 + cl] = o;
}

// ---------------- layer norm over 256: out = LN(x1 + x2) * gamma + beta
// 256 threads = 4 waves, one row per wave. Optionally also emits bf16 copy.
template <int EMIT_BF16>
__global__ __launch_bounds__(256) void ln_kernel(const float* __restrict__ x1,
                                                 const float* __restrict__ x2,
                                                 const float* __restrict__ gamma,
                                                 const float* __restrict__ beta,
                                                 float* __restrict__ out,
                                                 unsigned short* __restrict__ outb) {
  const int row = blockIdx.x * 4 + (threadIdx.x >> 6);
  const int lane = threadIdx.x & 63;
  float4 a = ((const float4*)(x1 + (size_t)row * 256))[lane];
  float4 b = ((const float4*)(x2 + (size_t)row * 256))[lane];
  float v0 = a.x + b.x, v1 = a.y + b.y, v2 = a.z + b.z, v3 = a.w + b.w;
  float s1 = v0 + v1 + v2 + v3;
  float s2 = v0 * v0 + v1 * v1 + v2 * v2 + v3 * v3;
#pragma unroll
  for (int o = 1; o < 64; o <<= 1) { s1 += __shfl_xor(s1, o); s2 += __shfl_xor(s2, o); }
  const float mean = s1 * (1.f / 256.f);
  const float var = s2 * (1.f / 256.f) - mean * mean;
  const float rstd = rsqrtf(var + 1e-5f);
  float4 gm = ((const float4*)gamma)[lane];
  float4 bt = ((const float4*)beta)[lane];
  float4 o4;
  o4.x = (v0 - mean) * rstd * gm.x + bt.x;
  o4.y = (v1 - mean) * rstd * gm.y + bt.y;
  o4.z = (v2 - mean) * rstd * gm.z + bt.z;
  o4.w = (v3 - mean) * rstd * gm.w + bt.w;
  ((float4*)(out + (size_t)row * 256))[lane] = o4;
  if (EMIT_BF16) {
    bf16x4 ob;
    ob.x = f2bf(o4.x); ob.y = f2bf(o4.y); ob.z = f2bf(o4.z); ob.w = f2bf(o4.w);
    ((bf16x4*)(outb + (size_t)row * 256))[lane] = ob;
  }
}

extern "C" void kernel_launch(void* const* d_in, const int* in_sizes, int n_in,
                              void* d_out, int out_size, void* d_ws, size_t ws_size,
                              hipStream_t stream) {
  (void)in_sizes; (void)n_in; (void)out_size; (void)ws_size;
  const float* cur_src = (const float*)d_in[0];
  const float* src_all = (const float*)d_in[1];
  const float* pos     = (const float*)d_in[2];
  const float* refp    = (const float*)d_in[3];
  const float* W_off   = (const float*)d_in[6];
  const float* b_off   = (const float*)d_in[7];
  const float* W_attn  = (const float*)d_in[8];
  const float* b_attn  = (const float*)d_in[9];
  const float* W_val   = (const float*)d_in[10];
  const float* b_val   = (const float*)d_in[11];
  const float* W_out   = (const float*)d_in[12];
  const float* b_out   = (const float*)d_in[13];
  const float* gamma1  = (const float*)d_in[14];
  const float* beta1   = (const float*)d_in[15];
  const float* W1      = (const float*)d_in[16];
  const float* b1      = (const float*)d_in[17];
  const float* W2      = (const float*)d_in[18];
  const float* b2      = (const float*)d_in[19];
  const float* gamma2  = (const float*)d_in[20];
  const float* beta2   = (const float*)d_in[21];
  float* out = (float*)d_out;

  // workspace layout (bytes); total ~209.4 MiB (unchanged)
  char* ws = (char*)d_ws;
  unsigned short* value = (unsigned short*)(ws + 0);          // 67,108,864 B; reused as FFN hidden
  unsigned short* qbuf  = (unsigned short*)(ws + 67108864);   // 16,777,216 B
  float* offbuf         = (float*)(ws + 83886080);            // 33,554,432 B; reused as ffn_out
  float* attnl          = (float*)(ws + 117440512);           // 16,777,216 B; reused as srcb_bf16
  unsigned short* attno = (unsigned short*)(ws + 134217728);  // 16,777,216 B
  float* src2           = (float*)(ws + 150994944);           // 33,554,432 B
  float* srcb           = (float*)(ws + 184549376);           // 33,554,432 B
  unsigned short* wt    = (unsigned short*)(ws + 218103808);  // bf16 weights (1.5 MB)
  unsigned short* wt_val  = wt;
  unsigned short* wt_qa   = wt + 65536;   // W_off(256xK) ++ W_attn(128xK) contiguous
  unsigned short* wt_out  = wt + 163840;
  unsigned short* wt_1    = wt + 229376;
  unsigned short* wt_2    = wt + 491520;
  unsigned short* srcb_bf = (unsigned short*)attnl;           // attnl dead after sample
  // inp_bf (131072x256 bf16 = 64 MiB) overlays src2+srcb (dead until out-proj)
  unsigned short* inp_bf  = (unsigned short*)src2;

  // prep: all weights -> bf16 NxK in one launch
  wtrans6_kernel<<<2944, 256, 0, stream>>>(W_val, W_off, W_attn, W_out, W1, W2, wt);

  // inp_bf = bf16(src_all + pos_flat); level-3 threads also emit qbuf
  addcvt_kernel<<<32768, 256, 0, stream>>>(src_all, pos, cur_src, inp_bf, qbuf);

  // value = inp_bf @ W_val + b_val  -> bf16
  gemm_lds_kernel<0, 1, 0><<<2048, 256, 0, stream>>>(
      inp_bf, wt_val, b_val, nullptr, value, nullptr, 131072, 256, 256, 2);
  // [off | attn logits] = qbuf @ [W_off | W_attn] (merged N=384, split epilogue)
  gemm_lds_kernel<0, 0, 1><<<768, 256, 0, stream>>>(
      qbuf, wt_qa, b_off, b_attn, offbuf, attnl, 32768, 384, 256, 3);
  // deformable sampling -> attn_out bf16 (8-lane subgroups: 32 per block)
  sample_kernel<<<8192, 256, 0, stream>>>(value, offbuf, attnl, refp,
                                          (unsigned int*)attno);
  // src2 = attn_out @ W_out + b_out (f32)  [overwrites inp_bf region: dead]
  gemm_lds_kernel<0, 0, 0><<<512, 256, 0, stream>>>(
      attno, wt_out, b_out, nullptr, src2, nullptr, 32768, 256, 256, 2);
  // src = LN(cur_src + src2) -> f32 srcb + bf16 srcb_bf
  ln_kernel<1><<<8192, 256, 0, stream>>>(cur_src, src2, gamma1, beta1, srcb, srcb_bf);
  // h = relu(src @ W1 + b1) -> bf16 (reuses value buffer; sample already done)
  gemm_lds_kernel<1, 1, 0><<<2048, 256, 0, stream>>>(
      srcb_bf, wt_1, b1, nullptr, value, nullptr, 32768, 1024, 256, 8);
  // ffn_out = h @ W2 + b2 (f32, reuses offbuf)
  gemm_lds_kernel<0, 0, 0><<<512, 256, 0, stream>>>(
      value, wt_2, b2, nullptr, offbuf, nullptr, 32768, 256, 1024, 2);
  // out = LN(src + ffn_out)
  ln_kernel<0><<<8192, 256, 0, stream>>>(srcb, offbuf, gamma2, beta2, out, nullptr);
}

// Round 3
// 610.450 us; speedup vs baseline: 1.0695x; 1.0695x over previous
//
#include <hip/hip_runtime.h>

// Problem constants
#define LQN   16384     // queries per batch (128*128)
#define LINN  65536     // value length per batch (4 levels * 16384)

typedef __attribute__((ext_vector_type(8))) short bf16x8;
typedef __attribute__((ext_vector_type(4))) float f32x4;
typedef __attribute__((ext_vector_type(4))) unsigned short bf16x4;

__device__ __forceinline__ unsigned short f2bf(float f) {
  unsigned u = __float_as_uint(f);
  u += 0x7FFFu + ((u >> 16) & 1u);      // round-to-nearest-even
  return (unsigned short)(u >> 16);
}

// ---------------- fused weight transpose+convert for all 6 weights.
// wt layout (shorts): W_val[0,65536) W_off[65536,131072) W_attn[131072,163840)
// W_out[163840,229376) W1[229376,491520) W2[491520,753664). Total 753664.
// NOTE: W_off then W_attn contiguous => combined 384xK matrix for the merged GEMM.
__global__ __launch_bounds__(256) void wtrans6_kernel(
    const float* __restrict__ Wv, const float* __restrict__ Wo,
    const float* __restrict__ Wa, const float* __restrict__ Wu,
    const float* __restrict__ W1, const float* __restrict__ W2,
    unsigned short* __restrict__ wt) {
  int idx = blockIdx.x * 256 + threadIdx.x;     // grid = 2944 blocks exactly
  const float* W; int K, N, base;
  if (idx < 131072) {
    if (idx < 65536) { W = Wv; K = 256; N = 256; base = 0; }
    else             { W = Wo; K = 256; N = 256; base = 65536; }
  } else if (idx < 229376) {
    if (idx < 163840) { W = Wa; K = 256; N = 128; base = 131072; }
    else              { W = Wu; K = 256; N = 256; base = 163840; }
  } else if (idx < 491520) { W = W1; K = 256; N = 1024; base = 229376; }
  else                     { W = W2; K = 1024; N = 256; base = 491520; }
  int local = idx - base;
  int n = local / K, k = local - n * K;
  wt[idx] = f2bf(W[(size_t)k * N + n]);
}

// ---------------- streaming add+convert: inp_bf = bf16(src_all + pos_flat).
// Level-3 threads additionally produce qbuf = bf16(cur_src + pos[:,3]),
// reusing the already-loaded pos register (saves re-streaming pos[:,3]).
__global__ __launch_bounds__(256) void addcvt_kernel(
    const float* __restrict__ src_all, const float* __restrict__ pos,
    const float* __restrict__ cur, unsigned short* __restrict__ inp_bf,
    unsigned short* __restrict__ qb) {
  size_t i = (size_t)blockIdx.x * 256 + threadIdx.x;  // < 8388608 (grid 32768)
  float4 a = ((const float4*)src_all)[i];
  float4 b = ((const float4*)pos)[i];     // pos flat matches src_all row order
  bf16x4 o;
  o.x = f2bf(a.x + b.x); o.y = f2bf(a.y + b.y);
  o.z = f2bf(a.z + b.z); o.w = f2bf(a.w + b.w);
  ((bf16x4*)inp_bf)[i] = o;
  size_t m = i & 4194303;                 // within-batch float4 index (2^22)
  if (m >= 3145728) {                     // level-3 slice of pos
    size_t jq = (i >> 22) * 1048576 + (m - 3145728);
    float4 cc = ((const float4*)cur)[jq];
    bf16x4 o2;
    o2.x = f2bf(cc.x + b.x); o2.y = f2bf(cc.y + b.y);
    o2.z = f2bf(cc.z + b.z); o2.w = f2bf(cc.w + b.w);
    ((bf16x4*)qb)[jq] = o2;
  }
}

// ---------------- bf16 MFMA GEMM, m97-style global_load_lds staging.
// A: M x K bf16 row-major. Bt: N x K bf16 (pre-transposed). 128x128 tile,
// BK=64, 4 waves (2x2 of 64x64). LDS unpadded, XOR source-swizzle: physical
// 16B chunk p of row r holds logical chunk p^(r&7); reads become 2-way (free).
// 1D grid, y-fast: by = bid % ny (N tile), bx = bid / ny (M tile).
// SPLIT=1: cols [0,256) -> Cp (stride 256) + bias, cols [256,384) -> Cp2
// (stride 128) + bias2 (block-uniform branch; tiles are pure).
// OUT_VAL=1: bf16 store transposed to value layout (n, h, pix, 32ch):
// addr = (((row>>16)*8 + (col>>5))*65536 + (row&65535))*32 + (col&31).
template <int DO_RELU, int OUT_BF16, int SPLIT, int OUT_VAL>
__global__ __launch_bounds__(256) void gemm_lds_kernel(
    const unsigned short* __restrict__ A, const unsigned short* __restrict__ Bt,
    const float* __restrict__ bias, const float* __restrict__ bias2,
    void* __restrict__ Cp, float* __restrict__ Cp2,
    int M, int N, int K, int ny) {
  __shared__ unsigned short As[128 * 64];
  __shared__ unsigned short Bs[128 * 64];
  const int bid = blockIdx.x;
  const int by = bid % ny, bx = bid / ny;
  const int m0 = bx * 128, n0 = by * 128;
  const int tid = threadIdx.x;
  const int wave = tid >> 6, lane = tid & 63;
  const int wm = (wave >> 1) * 64, wn = (wave & 1) * 64;
  const int l15 = lane & 15, quad = lane >> 4;
  const int rl = lane >> 3;                 // row within 8-row slab
  const int cl = (lane & 7) ^ rl;           // swizzled source chunk (16B units)

  f32x4 acc[4][4];
#pragma unroll
  for (int i = 0; i < 4; i++)
#pragma unroll
    for (int j = 0; j < 4; j++)
#pragma unroll
      for (int r = 0; r < 4; r++) acc[i][j][r] = 0.f;

  const unsigned short* Abase = A + (size_t)m0 * K + cl * 8;
  const unsigned short* Bbase = Bt + (size_t)n0 * K + cl * 8;

  for (int k0 = 0; k0 < K; k0 += 64) {
    // ---- async stage: each wave covers 32 rows of As and Bs (4 issues each)
#pragma unroll
    for (int t = 0; t < 4; t++) {
      const int row = wave * 32 + t * 8 + rl;
      __builtin_amdgcn_global_load_lds(
          (const __attribute__((address_space(1))) void*)(Abase + (size_t)row * K + k0),
          (__attribute__((address_space(3))) void*)(As + (wave * 32 + t * 8) * 64),
          16, 0, 0);
      __builtin_amdgcn_global_load_lds(
          (const __attribute__((address_space(1))) void*)(Bbase + (size_t)row * K + k0),
          (__attribute__((address_space(3))) void*)(Bs + (wave * 32 + t * 8) * 64),
          16, 0, 0);
    }
    __syncthreads();   // drains vmcnt(0) then barrier: LDS tiles ready
#pragma unroll
    for (int kk = 0; kk < 2; kk++) {
      bf16x8 af[4], bfr[4];
#pragma unroll
      for (int i = 0; i < 4; i++) {
        const int row = wm + i * 16 + l15;
        af[i] = *(const bf16x8*)&As[row * 64 + (((quad + 4 * kk) ^ (row & 7)) * 8)];
      }
#pragma unroll
      for (int j = 0; j < 4; j++) {
        const int row = wn + j * 16 + l15;
        bfr[j] = *(const bf16x8*)&Bs[row * 64 + (((quad + 4 * kk) ^ (row & 7)) * 8)];
      }
#pragma unroll
      for (int i = 0; i < 4; i++)
#pragma unroll
        for (int j = 0; j < 4; j++)
          acc[i][j] = __builtin_amdgcn_mfma_f32_16x16x32_bf16(af[i], bfr[j], acc[i][j], 0, 0, 0);
    }
    __syncthreads();   // protect LDS before next-iter overwrite
  }
  // ---- epilogue: bias (+relu), store
#pragma unroll
  for (int i = 0; i < 4; i++) {
#pragma unroll
    for (int j = 0; j < 4; j++) {
      const int col = n0 + wn + j * 16 + l15;
      float bv;
      if (SPLIT) bv = (col < 256) ? bias[col] : bias2[col - 256];
      else       bv = bias[col];
#pragma unroll
      for (int r = 0; r < 4; r++) {
        const int row = m0 + wm + i * 16 + quad * 4 + r;
        float v = acc[i][j][r] + bv;
        if (DO_RELU) v = fmaxf(v, 0.f);
        if (SPLIT) {
          if (col < 256) ((float*)Cp)[(size_t)row * 256 + col] = v;
          else           Cp2[(size_t)row * 128 + (col - 256)] = v;
        } else if (OUT_BF16) {
          size_t addr;
          if (OUT_VAL)
            addr = (((size_t)(row >> 16) * 8 + (col >> 5)) * 65536 +
                    (size_t)(row & 65535)) * 32 + (col & 31);
          else
            addr = (size_t)row * N + col;
          ((unsigned short*)Cp)[addr] = f2bf(v);
        } else {
          ((float*)Cp)[(size_t)row * N + col] = v;
        }
      }
    }
  }
}

// ---------------- deformable sampling (v3)
// value: (2, 8, LINN, 32) bf16  [head-major layout!]; offs: (2,LQ,8,4,4,2) f32;
// attnl: (2,LQ,128) f32; refp: (2,LQ,4,2) f32; out: (2,LQ,8,32) bf16.
// 8-lane subgroup per (n,lq,h). Block ordering is HEAD-MAJOR (all resident
// blocks sample the same head's 8 MiB slice -> per-XCD L2 working set 8x
// smaller). Per bilinear row the (x0,x0+1) pixel pair is one contiguous
// 128 B segment: one dwordx4 per lane, lanes 0-3 get left pixel channels,
// 4-7 right pixel; final channel combine via shfl_xor(.,4). LDS row stride
// 132 floats -> broadcast ds_read_b128 conflict-free across subgroups.
__global__ __launch_bounds__(256) void sample_kernel(
    const unsigned short* __restrict__ value, const float* __restrict__ offs,
    const float* __restrict__ attnl, const float* __restrict__ refp,
    unsigned int* __restrict__ attn_out) {
  __shared__ float wlds[32][132];
  const int tid = threadIdx.x;
  const int sub = tid >> 3;                // 0..31
  const int cl  = tid & 7;                 // lane in subgroup
  const int gb = blockIdx.x * 32 + sub;    // head-major linear id, < 262144
  const int h  = gb >> 15;                 // head (uniform per block)
  const int nl = gb & 32767;               // n*LQ + lq
  const int n  = nl >> 14;
  const int g  = nl * 8 + h;               // row id in offs / attn_out

  // ---- distributed softmax over 16 (level,point) logits; lane owns 2cl,2cl+1
  const float* lg = attnl + (size_t)nl * 128 + h * 16;
  const float2 l2 = *(const float2*)(lg + 2 * cl);
  float mx = fmaxf(l2.x, l2.y);
#pragma unroll
  for (int o = 1; o < 8; o <<= 1) mx = fmaxf(mx, __shfl_xor(mx, o, 8));
  const float e0 = __expf(l2.x - mx), e1 = __expf(l2.y - mx);
  float s = e0 + e1;
#pragma unroll
  for (int o = 1; o < 8; o <<= 1) s += __shfl_xor(s, o, 8);
  const float inv = 1.f / s;

  // ---- prep 2 points per lane (pt = 2cl, 2cl+1; both in level cl>>1) -> LDS
  const float4 o4 = *(const float4*)(offs + (size_t)g * 32 + 4 * cl);
  const float2 r2 = *(const float2*)(refp + ((size_t)nl * 4 + (cl >> 1)) * 2);
#pragma unroll
  for (int q = 0; q < 2; q++) {
    const float ox = (q == 0) ? o4.x : o4.z;
    const float oy = (q == 0) ? o4.y : o4.w;
    const float aw = ((q == 0) ? e0 : e1) * inv;
    const float x = fmaf(r2.x, 128.f, ox - 0.5f);   // (ref + off/128)*128 - 0.5
    const float y = fmaf(r2.y, 128.f, oy - 0.5f);
    const float xf = floorf(x), yf = floorf(y);
    const float fx = x - xf, fy = y - yf;
    const int x0 = (int)xf, y0 = (int)yf;
    const float wx0 = (x0 >= 0 && x0 <= 127) ? (1.f - fx) : 0.f;
    const float wx1 = (x0 >= -1 && x0 <= 126) ? fx : 0.f;
    const float wy0 = ((y0 >= 0 && y0 <= 127) ? (1.f - fy) : 0.f) * aw;
    const float wy1 = ((y0 >= -1 && y0 <= 126) ? fy : 0.f) * aw;
    // pixel pair (px, px+1) always within the row; corner weights remapped
    const int px = min(max(x0, 0), 126);
    const float wl = (px == x0) ? wx0 : ((px == x0 + 1) ? wx1 : 0.f);
    const float wr = (px + 1 == x0) ? wx0 : ((px == x0) ? wx1 : 0.f);
    const int yc0 = min(max(y0, 0), 127), yc1 = min(max(y0 + 1, 0), 127);
    const int lb = (cl >> 1) * 16384;
    const unsigned ot = (unsigned)(lb + yc0 * 128 + px) * 64u;  // byte offsets
    const unsigned ob = (unsigned)(lb + yc1 * 128 + px) * 64u;
    float* wp = &wlds[sub][(2 * cl + q) * 8];
    wp[0] = wl * wy0; wp[1] = wr * wy0;
    wp[2] = wl * wy1; wp[3] = wr * wy1;
    wp[4] = __uint_as_float(ot); wp[5] = __uint_as_float(ob);
  }
  // subgroup == 8 lanes of one wave: wave-synchronous, no barrier needed

  // ---- gather loop: 16 points x 2 rows, one dwordx4 (128 B/subgroup) each
  const char* hb = (const char*)value + (((size_t)(n * 8 + h)) << 22) + cl * 16;
  float a0 = 0.f, a1 = 0.f, a2 = 0.f, a3 = 0.f;
  float a4 = 0.f, a5 = 0.f, a6 = 0.f, a7 = 0.f;
#pragma unroll
  for (int p = 0; p < 16; p++) {
    const float4 w4 = *(const float4*)&wlds[sub][p * 8];
    const float2 of2 = *(const float2*)&wlds[sub][p * 8 + 4];
    const uint4 vt = *(const uint4*)(hb + __float_as_uint(of2.x));
    const uint4 vb = *(const uint4*)(hb + __float_as_uint(of2.y));
    const float wtop = (cl < 4) ? w4.x : w4.y;   // top row: left/right weight
    const float wbot = (cl < 4) ? w4.z : w4.w;   // bottom row
#define ACC8(vv, wgt)                                              \
    a0 = fmaf(wgt, __uint_as_float((vv).x << 16), a0);             \
    a1 = fmaf(wgt, __uint_as_float((vv).x & 0xFFFF0000u), a1);     \
    a2 = fmaf(wgt, __uint_as_float((vv).y << 16), a2);             \
    a3 = fmaf(wgt, __uint_as_float((vv).y & 0xFFFF0000u), a3);     \
    a4 = fmaf(wgt, __uint_as_float((vv).z << 16), a4);             \
    a5 = fmaf(wgt, __uint_as_float((vv).z & 0xFFFF0000u), a5);     \
    a6 = fmaf(wgt, __uint_as_float((vv).w << 16), a6);             \
    a7 = fmaf(wgt, __uint_as_float((vv).w & 0xFFFF0000u), a7);
    ACC8(vt, wtop)
    ACC8(vb, wbot)
#undef ACC8
  }
  // combine left/right pixel halves: lanes 0-3 end with full channel sums
  a0 += __shfl_xor(a0, 4, 8); a1 += __shfl_xor(a1, 4, 8);
  a2 += __shfl_xor(a2, 4, 8); a3 += __shfl_xor(a3, 4, 8);
  a4 += __shfl_xor(a4, 4, 8); a5 += __shfl_xor(a5, 4, 8);
  a6 += __shfl_xor(a6, 4, 8); a7 += __shfl_xor(a7, 4, 8);
  if (cl < 4) {
    uint4 o;
    o.x = (unsigned)f2bf(a0) | ((unsigned)f2bf(a1) << 16);
    o.y = (unsigned)f2bf(a2) | ((unsigned)f2bf(a3) << 16);
    o.z = (unsigned)f2bf(a4) | ((unsigned)f2bf(a5) << 16);
    o.w = (unsigned)f2bf(a6) | ((unsigned)f2bf(a7) << 16);
    ((uint4*)attn_out)[(size_t)g * 4 + cl] = o;
  }
}

// ---------------- layer norm over 256: out = LN(x1 + x2) * gamma + beta
// 256 threads = 4 waves, one row per wave. Optionally also emits bf16 copy.
template <int EMIT_BF16>
__global__ __launch_bounds__(256) void ln_kernel(const float* __restrict__ x1,
                                                 const float* __restrict__ x2,
                                                 const float* __restrict__ gamma,
                                                 const float* __restrict__ beta,
                                                 float* __restrict__ out,
                                                 unsigned short* __restrict__ outb) {
  const int row = blockIdx.x * 4 + (threadIdx.x >> 6);
  const int lane = threadIdx.x & 63;
  float4 a = ((const float4*)(x1 + (size_t)row * 256))[lane];
  float4 b = ((const float4*)(x2 + (size_t)row * 256))[lane];
  float v0 = a.x + b.x, v1 = a.y + b.y, v2 = a.z + b.z, v3 = a.w + b.w;
  float s1 = v0 + v1 + v2 + v3;
  float s2 = v0 * v0 + v1 * v1 + v2 * v2 + v3 * v3;
#pragma unroll
  for (int o = 1; o < 64; o <<= 1) { s1 += __shfl_xor(s1, o); s2 += __shfl_xor(s2, o); }
  const float mean = s1 * (1.f / 256.f);
  const float var = s2 * (1.f / 256.f) - mean * mean;
  const float rstd = rsqrtf(var + 1e-5f);
  float4 gm = ((const float4*)gamma)[lane];
  float4 bt = ((const float4*)beta)[lane];
  float4 o4;
  o4.x = (v0 - mean) * rstd * gm.x + bt.x;
  o4.y = (v1 - mean) * rstd * gm.y + bt.y;
  o4.z = (v2 - mean) * rstd * gm.z + bt.z;
  o4.w = (v3 - mean) * rstd * gm.w + bt.w;
  ((float4*)(out + (size_t)row * 256))[lane] = o4;
  if (EMIT_BF16) {
    bf16x4 ob;
    ob.x = f2bf(o4.x); ob.y = f2bf(o4.y); ob.z = f2bf(o4.z); ob.w = f2bf(o4.w);
    ((bf16x4*)(outb + (size_t)row * 256))[lane] = ob;
  }
}

extern "C" void kernel_launch(void* const* d_in, const int* in_sizes, int n_in,
                              void* d_out, int out_size, void* d_ws, size_t ws_size,
                              hipStream_t stream) {
  (void)in_sizes; (void)n_in; (void)out_size; (void)ws_size;
  const float* cur_src = (const float*)d_in[0];
  const float* src_all = (const float*)d_in[1];
  const float* pos     = (const float*)d_in[2];
  const float* refp    = (const float*)d_in[3];
  const float* W_off   = (const float*)d_in[6];
  const float* b_off   = (const float*)d_in[7];
  const float* W_attn  = (const float*)d_in[8];
  const float* b_attn  = (const float*)d_in[9];
  const float* W_val   = (const float*)d_in[10];
  const float* b_val   = (const float*)d_in[11];
  const float* W_out   = (const float*)d_in[12];
  const float* b_out   = (const float*)d_in[13];
  const float* gamma1  = (const float*)d_in[14];
  const float* beta1   = (const float*)d_in[15];
  const float* W1      = (const float*)d_in[16];
  const float* b1      = (const float*)d_in[17];
  const float* W2      = (const float*)d_in[18];
  const float* b2      = (const float*)d_in[19];
  const float* gamma2  = (const float*)d_in[20];
  const float* beta2   = (const float*)d_in[21];
  float* out = (float*)d_out;

  // workspace layout (bytes); total ~209.4 MiB (unchanged)
  char* ws = (char*)d_ws;
  unsigned short* value = (unsigned short*)(ws + 0);          // 67,108,864 B; reused as FFN hidden
  unsigned short* qbuf  = (unsigned short*)(ws + 67108864);   // 16,777,216 B
  float* offbuf         = (float*)(ws + 83886080);            // 33,554,432 B; reused as ffn_out
  float* attnl          = (float*)(ws + 117440512);           // 16,777,216 B; reused as srcb_bf16
  unsigned short* attno = (unsigned short*)(ws + 134217728);  // 16,777,216 B
  float* src2           = (float*)(ws + 150994944);           // 33,554,432 B
  float* srcb           = (float*)(ws + 184549376);           // 33,554,432 B
  unsigned short* wt    = (unsigned short*)(ws + 218103808);  // bf16 weights (1.5 MB)
  unsigned short* wt_val  = wt;
  unsigned short* wt_qa   = wt + 65536;   // W_off(256xK) ++ W_attn(128xK) contiguous
  unsigned short* wt_out  = wt + 163840;
  unsigned short* wt_1    = wt + 229376;
  unsigned short* wt_2    = wt + 491520;
  unsigned short* srcb_bf = (unsigned short*)attnl;           // attnl dead after sample
  // inp_bf (131072x256 bf16 = 64 MiB) overlays src2+srcb (dead until out-proj)
  unsigned short* inp_bf  = (unsigned short*)src2;

  // prep: all weights -> bf16 NxK in one launch
  wtrans6_kernel<<<2944, 256, 0, stream>>>(W_val, W_off, W_attn, W_out, W1, W2, wt);

  // inp_bf = bf16(src_all + pos_flat); level-3 threads also emit qbuf
  addcvt_kernel<<<32768, 256, 0, stream>>>(src_all, pos, cur_src, inp_bf, qbuf);

  // value = inp_bf @ W_val + b_val -> bf16, stored head-major (n,h,pix,ch)
  gemm_lds_kernel<0, 1, 0, 1><<<2048, 256, 0, stream>>>(
      inp_bf, wt_val, b_val, nullptr, value, nullptr, 131072, 256, 256, 2);
  // [off | attn logits] = qbuf @ [W_off | W_attn] (merged N=384, split epilogue)
  gemm_lds_kernel<0, 0, 1, 0><<<768, 256, 0, stream>>>(
      qbuf, wt_qa, b_off, b_attn, offbuf, attnl, 32768, 384, 256, 3);
  // deformable sampling -> attn_out bf16 (head-major block order)
  sample_kernel<<<8192, 256, 0, stream>>>(value, offbuf, attnl, refp,
                                          (unsigned int*)attno);
  // src2 = attn_out @ W_out + b_out (f32)  [overwrites inp_bf region: dead]
  gemm_lds_kernel<0, 0, 0, 0><<<512, 256, 0, stream>>>(
      attno, wt_out, b_out, nullptr, src2, nullptr, 32768, 256, 256, 2);
  // src = LN(cur_src + src2) -> f32 srcb + bf16 srcb_bf
  ln_kernel<1><<<8192, 256, 0, stream>>>(cur_src, src2, gamma1, beta1, srcb, srcb_bf);
  // h = relu(src @ W1 + b1) -> bf16 (reuses value buffer; sample already done)
  gemm_lds_kernel<1, 1, 0, 0><<<2048, 256, 0, stream>>>(
      srcb_bf, wt_1, b1, nullptr, value, nullptr, 32768, 1024, 256, 8);
  // ffn_out = h @ W2 + b2 (f32, reuses offbuf)
  gemm_lds_kernel<0, 0, 0, 0><<<512, 256, 0, stream>>>(
      value, wt_2, b2, nullptr, offbuf, nullptr, 32768, 256, 1024, 2);
  // out = LN(src + ffn_out)
  ln_kernel<0><<<8192, 256, 0, stream>>>(srcb, offbuf, gamma2, beta2, out, nullptr);
}